// Round 1
// baseline (13000.520 us; speedup 1.0000x reference)
//
#include <hip/hip_runtime.h>

using u16 = unsigned short;
using u32 = unsigned int;
using f32x4 = __attribute__((ext_vector_type(4))) float;
using short8 = __attribute__((ext_vector_type(8))) short;

#define TT 100
#define BB 128
#define EE 2048
#define HH 1024
#define DD 256
#define VV 2048
#define H4 4096
#define NPRE 8704            // 4096(PX0) + 4096(PX1) + 256(PR0) + 256(PR1)
#define MPRE (TT * BB)       // 12800

__device__ __forceinline__ float bf2f(u16 u) { return __uint_as_float(((u32)u) << 16); }
__device__ __forceinline__ u16 f2bf(float f) {
  u32 x = __float_as_uint(f);
  x += 0x7fffu + ((x >> 16) & 1u);   // round-to-nearest-even
  return (u16)(x >> 16);
}
__device__ __forceinline__ float sigm(float x) { return 1.0f / (1.0f + expf(-x)); }

// ---------------------------------------------------------------------------
// xs builder: row = t*B+b ; t==0 -> SOS one-hot, else input_seq[b, t-1, :]
// ---------------------------------------------------------------------------
__global__ __launch_bounds__(256) void build_xs(const float* __restrict__ inseq,
                                                u16* __restrict__ xs) {
  const int row = blockIdx.x;       // 0..12799
  const int e0 = threadIdx.x << 3;  // 0..2040
  const int t = row >> 7, b = row & 127;
  u16 v[8];
  if (t == 0) {
#pragma unroll
    for (int i = 0; i < 8; ++i) v[i] = 0;
    if (e0 == 0) v[0] = 0x3F80;     // bf16(1.0)
  } else {
    const float* src = inseq + ((size_t)b * TT + (t - 1)) * EE + e0;
#pragma unroll
    for (int i = 0; i < 8; ++i) v[i] = f2bf(src[i]);
  }
  uint4 o;
  o.x = (u32)v[0] | ((u32)v[1] << 16);
  o.y = (u32)v[2] | ((u32)v[3] << 16);
  o.z = (u32)v[4] | ((u32)v[5] << 16);
  o.w = (u32)v[6] | ((u32)v[7] << 16);
  *(uint4*)(xs + (size_t)row * EE + e0) = o;
}

// ---------------------------------------------------------------------------
// transpose + convert: out[n*ldout + k] = bf16(in[k*ldin + n]); dims %32==0
// ---------------------------------------------------------------------------
__global__ __launch_bounds__(256) void tconv(const float* __restrict__ in, int ldin,
                                             u16* __restrict__ out, int ldout) {
  __shared__ float tile[32][33];
  const int k0 = blockIdx.y << 5, n0 = blockIdx.x << 5;
  const int tx = threadIdx.x, ty = threadIdx.y;
#pragma unroll
  for (int i = 0; i < 32; i += 8)
    tile[ty + i][tx] = in[(size_t)(k0 + ty + i) * ldin + n0 + tx];
  __syncthreads();
#pragma unroll
  for (int i = 0; i < 32; i += 8)
    out[(size_t)(n0 + ty + i) * ldout + k0 + tx] = f2bf(tile[tx][ty + i]);
}

__global__ __launch_bounds__(256) void k_biascat(
    const float* w2h_b0, const float* h2h_b0, const float* w2h_b1, const float* h2h_b1,
    const float* w2hr_b0, const float* w2hr_b1, float* biascat) {
  int g = blockIdx.x * 256 + threadIdx.x;
  if (g >= NPRE) return;
  float v;
  if (g < 4096) v = w2h_b0[g] + h2h_b0[g];
  else if (g < 8192) v = w2h_b1[g - 4096] + h2h_b1[g - 4096];
  else if (g < 8448) v = w2hr_b0[g - 8192];
  else v = w2hr_b1[g - 8448];
  biascat[g] = v;
}

// hist slot0 = bf16(h0) for both layer halves; c0=c1=h0 ; d0=d1=dt0 (ping slot 0)
__global__ __launch_bounds__(256) void k_init(const float* __restrict__ h0,
                                              const float* __restrict__ dt0,
                                              u16* __restrict__ hist, float* c0, float* c1,
                                              float* d0, float* d1) {
  int g = blockIdx.x * 256 + threadIdx.x;  // 0..262143
  int b = g >> 11, j = g & 2047;
  float hv = h0[b * HH + (j & 1023)];
  hist[g] = f2bf(hv);
  if (j < HH) { c0[b * HH + j] = hv; c1[b * HH + j] = hv; }
  if (j < DD) { float dv = dt0[b * DD + j]; d0[b * DD + j] = dv; d1[b * DD + j] = dv; }
}

// ---------------------------------------------------------------------------
// big GEMM: C(MxN) = A(MxK,bf16) * Bt(NxK,bf16)^T + bias ; 128x128 tile, 4 waves
// MODE 0: C bf16 row-major (Pcat). MODE 1: C fp32 scattered to out[(b*T+t)*V]
// ---------------------------------------------------------------------------
template <int MODE>
__global__ __launch_bounds__(256) void gemm_big(const u16* __restrict__ A,
                                                const u16* __restrict__ Bt,
                                                const float* __restrict__ bias,
                                                void* __restrict__ Cv, int N, int K) {
  __shared__ __align__(16) u16 lA[128 * 72];
  __shared__ __align__(16) u16 lB[128 * 72];
  const int tid = threadIdx.x;
  const int lane = tid & 63;
  const int wid = tid >> 6;
  const int wr = wid >> 1, wc = wid & 1;
  const int nt = N >> 7;
  const int bm = (blockIdx.x / nt) << 7;
  const int bn = (blockIdx.x % nt) << 7;
  f32x4 acc[4][4] = {};
  const int r = tid >> 1;          // 0..127
  const int kh = (tid & 1) << 5;   // 0 / 32
  const u16* ga = A + (size_t)(bm + r) * K + kh;
  const u16* gb = Bt + (size_t)(bn + r) * K + kh;
  for (int k0 = 0; k0 < K; k0 += 64) {
    uint4 a0 = *(const uint4*)(ga + k0);
    uint4 a1 = *(const uint4*)(ga + k0 + 8);
    uint4 a2 = *(const uint4*)(ga + k0 + 16);
    uint4 a3 = *(const uint4*)(ga + k0 + 24);
    uint4 b0 = *(const uint4*)(gb + k0);
    uint4 b1 = *(const uint4*)(gb + k0 + 8);
    uint4 b2 = *(const uint4*)(gb + k0 + 16);
    uint4 b3 = *(const uint4*)(gb + k0 + 24);
    __syncthreads();
    *(uint4*)(lA + r * 72 + kh) = a0;
    *(uint4*)(lA + r * 72 + kh + 8) = a1;
    *(uint4*)(lA + r * 72 + kh + 16) = a2;
    *(uint4*)(lA + r * 72 + kh + 24) = a3;
    *(uint4*)(lB + r * 72 + kh) = b0;
    *(uint4*)(lB + r * 72 + kh + 8) = b1;
    *(uint4*)(lB + r * 72 + kh + 16) = b2;
    *(uint4*)(lB + r * 72 + kh + 24) = b3;
    __syncthreads();
#pragma unroll
    for (int ks = 0; ks < 2; ++ks) {
      const int kk = ks * 32 + ((lane >> 4) << 3);
      short8 af[4], bf[4];
#pragma unroll
      for (int i = 0; i < 4; ++i) {
        af[i] = *(const short8*)(lA + (wr * 64 + i * 16 + (lane & 15)) * 72 + kk);
        bf[i] = *(const short8*)(lB + (wc * 64 + i * 16 + (lane & 15)) * 72 + kk);
      }
#pragma unroll
      for (int i = 0; i < 4; ++i)
#pragma unroll
        for (int j = 0; j < 4; ++j)
          acc[i][j] = __builtin_amdgcn_mfma_f32_16x16x32_bf16(af[i], bf[j], acc[i][j], 0, 0, 0);
    }
  }
#pragma unroll
  for (int i = 0; i < 4; ++i) {
#pragma unroll
    for (int j = 0; j < 4; ++j) {
      const int col = bn + wc * 64 + j * 16 + (lane & 15);
      const int rb = bm + wr * 64 + i * 16 + ((lane >> 4) << 2);
      const float bv = bias[col];
#pragma unroll
      for (int rg = 0; rg < 4; ++rg) {
        const int row = rb + rg;
        const float v = acc[i][j][rg] + bv;
        if (MODE == 0) {
          ((u16*)Cv)[(size_t)row * N + col] = f2bf(v);
        } else {
          const int tt = row >> 7, b = row & 127;
          ((float*)Cv)[((size_t)b * TT + tt) * VV + col] = v;
        }
      }
    }
  }
}

// ---------------------------------------------------------------------------
// 64x64-tile GEMM core for sequential stages (4 waves of 32x32, K-step 64)
// ---------------------------------------------------------------------------
__device__ __forceinline__ void gemm64(const u16* __restrict__ A, int lda,
                                       const u16* __restrict__ Bt, int ldb, int K,
                                       u16* lA, u16* lB, f32x4 acc[2][2]) {
  const int tid = threadIdx.x;
  const int lane = tid & 63;
  const int wid = tid >> 6;
  const int wr = wid >> 1, wc = wid & 1;
  const int r = tid >> 2;          // 0..63
  const int kq = (tid & 3) << 4;   // 0,16,32,48
  const u16* ga = A + (size_t)r * lda + kq;
  const u16* gb = Bt + (size_t)r * ldb + kq;
  for (int k0 = 0; k0 < K; k0 += 64) {
    uint4 a0 = *(const uint4*)(ga + k0);
    uint4 a1 = *(const uint4*)(ga + k0 + 8);
    uint4 b0 = *(const uint4*)(gb + k0);
    uint4 b1 = *(const uint4*)(gb + k0 + 8);
    __syncthreads();
    *(uint4*)(lA + r * 72 + kq) = a0;
    *(uint4*)(lA + r * 72 + kq + 8) = a1;
    *(uint4*)(lB + r * 72 + kq) = b0;
    *(uint4*)(lB + r * 72 + kq + 8) = b1;
    __syncthreads();
#pragma unroll
    for (int ks = 0; ks < 2; ++ks) {
      const int kk = ks * 32 + ((lane >> 4) << 3);
      const short8 af0 = *(const short8*)(lA + (wr * 32 + (lane & 15)) * 72 + kk);
      const short8 af1 = *(const short8*)(lA + (wr * 32 + 16 + (lane & 15)) * 72 + kk);
      const short8 bf0 = *(const short8*)(lB + (wc * 32 + (lane & 15)) * 72 + kk);
      const short8 bf1 = *(const short8*)(lB + (wc * 32 + 16 + (lane & 15)) * 72 + kk);
      acc[0][0] = __builtin_amdgcn_mfma_f32_16x16x32_bf16(af0, bf0, acc[0][0], 0, 0, 0);
      acc[0][1] = __builtin_amdgcn_mfma_f32_16x16x32_bf16(af0, bf1, acc[0][1], 0, 0, 0);
      acc[1][0] = __builtin_amdgcn_mfma_f32_16x16x32_bf16(af1, bf0, acc[1][0], 0, 0, 0);
      acc[1][1] = __builtin_amdgcn_mfma_f32_16x16x32_bf16(af1, bf1, acc[1][1], 0, 0, 0);
    }
  }
  __syncthreads();
}

// K=256 variant: A (dt) already staged in ldsA[64][264]; only B streamed
__device__ __forceinline__ void gemm_ccA(const u16* __restrict__ Bt, const u16* lA, u16* lB,
                                         f32x4 acc[2][2]) {
  const int tid = threadIdx.x;
  const int lane = tid & 63;
  const int wid = tid >> 6;
  const int wr = wid >> 1, wc = wid & 1;
  const int r = tid >> 2;
  const int kq = (tid & 3) << 4;
  const u16* gb = Bt + (size_t)r * DD + kq;
  for (int k0 = 0; k0 < 256; k0 += 64) {
    uint4 b0 = *(const uint4*)(gb + k0);
    uint4 b1 = *(const uint4*)(gb + k0 + 8);
    __syncthreads();
    *(uint4*)(lB + r * 72 + kq) = b0;
    *(uint4*)(lB + r * 72 + kq + 8) = b1;
    __syncthreads();
#pragma unroll
    for (int ks = 0; ks < 2; ++ks) {
      const int kk = ks * 32 + ((lane >> 4) << 3);
      const int ka = k0 + kk;
      const short8 af0 = *(const short8*)(lA + (wr * 32 + (lane & 15)) * 264 + ka);
      const short8 af1 = *(const short8*)(lA + (wr * 32 + 16 + (lane & 15)) * 264 + ka);
      const short8 bf0 = *(const short8*)(lB + (wc * 32 + (lane & 15)) * 72 + kk);
      const short8 bf1 = *(const short8*)(lB + (wc * 32 + 16 + (lane & 15)) * 72 + kk);
      acc[0][0] = __builtin_amdgcn_mfma_f32_16x16x32_bf16(af0, bf0, acc[0][0], 0, 0, 0);
      acc[0][1] = __builtin_amdgcn_mfma_f32_16x16x32_bf16(af0, bf1, acc[0][1], 0, 0, 0);
      acc[1][0] = __builtin_amdgcn_mfma_f32_16x16x32_bf16(af1, bf0, acc[1][0], 0, 0, 0);
      acc[1][1] = __builtin_amdgcn_mfma_f32_16x16x32_bf16(af1, bf1, acc[1][1], 0, 0, 0);
    }
  }
  __syncthreads();
}

#define EPI(...)                                                          \
  do {                                                                    \
    _Pragma("unroll") for (int ei = 0; ei < 2; ++ei) {                    \
      _Pragma("unroll") for (int ej = 0; ej < 2; ++ej) {                  \
        const int col = n0 + wc * 32 + ej * 16 + (lane & 15);             \
        const int rb = m0 + wr * 32 + ei * 16 + ((lane >> 4) << 2);       \
        _Pragma("unroll") for (int rg = 0; rg < 4; ++rg) {                \
          const int row = rb + rg;                                        \
          const float av = acc[ei][ej][rg];                               \
          __VA_ARGS__                                                     \
        }                                                                 \
      }                                                                   \
    }                                                                     \
  } while (0)

struct SeqArgs {
  const u16* Pcat;
  const u16* h2h0T;    // (4096,1024)
  const u16* w1sT;     // (4096,2048)  k<1024: w2h_W1[E:]^T, k>=1024: h2h_W1^T
  const u16* hrsT;     // (256,2048)   k<1024: h2hr_W0^T,   k>=1024: h2hr_W1^T
  const u16* w2hr1hT;  // (256,1024)
  const u16* dc0T;     // (1024,256)
  const u16* dc1T;
  const float* hb0;    // h2hr_b0
  const float* hb1;
  u16* hist;           // (T+1, 128, 2048) bf16
  float* g0buf;        // (128,4096)
  float* g1p0;
  float* g1p1;
  float* rcp0;         // (128,256)
  float* rcp1;
  float* c0;
  float* c1;
  float* d0;           // [2][128*256] ping-pong
  float* d1;
  u16* dt1bf;          // (128,256)
};

// Stage 1: g0 (K=1024) ; rc partials rcp0/rcp1 (K=1024 each).  grid=144
__global__ __launch_bounds__(256) void stage1(SeqArgs a, int t) {
  __shared__ __align__(16) u16 ldsA[64 * 72];
  __shared__ __align__(16) u16 ldsB[64 * 72];
  const int tid = threadIdx.x, lane = tid & 63, wid = tid >> 6;
  const int wr = wid >> 1, wc = wid & 1;
  const int wg = blockIdx.x;
  const size_t slot0 = (size_t)t * (BB * 2048);
  const u16* px = a.Pcat + (size_t)t * (BB * NPRE);
  if (wg < 128) {
    const int m0 = (wg >> 6) << 6, n0 = (wg & 63) << 6;
    f32x4 acc[2][2] = {};
    gemm64(a.hist + slot0 + (size_t)m0 * 2048, 2048, a.h2h0T + (size_t)n0 * HH, HH, HH,
           ldsA, ldsB, acc);
    EPI(a.g0buf[row * H4 + col] = av + bf2f(px[(size_t)row * NPRE + col]););
  } else if (wg < 136) {
    const int jid = wg - 128;
    const int m0 = (jid >> 2) << 6, n0 = (jid & 3) << 6;
    f32x4 acc[2][2] = {};
    gemm64(a.hist + slot0 + (size_t)m0 * 2048, 2048, a.hrsT + (size_t)n0 * 2048, 2048, HH,
           ldsA, ldsB, acc);
    EPI(a.rcp0[row * DD + col] = av;);
  } else {
    const int jid = wg - 136;
    const int m0 = (jid >> 2) << 6, n0 = (jid & 3) << 6;
    f32x4 acc[2][2] = {};
    gemm64(a.hist + slot0 + (size_t)m0 * 2048 + 1024, 2048,
           a.hrsT + (size_t)n0 * 2048 + 1024, 2048, HH, ldsA, ldsB, acc);
    EPI(a.rcp1[row * DD + col] = av;);
  }
}

// Stage 2: dt0 on-the-fly -> cc0 (K=256) -> c0,h0 ; plus h1_old copy. grid=40
__global__ __launch_bounds__(256) void stage2(SeqArgs a, int t) {
  __shared__ __align__(16) u16 ldsA[64 * 264];
  __shared__ __align__(16) u16 ldsB[64 * 72];
  const int tid = threadIdx.x, lane = tid & 63, wid = tid >> 6;
  const int wr = wid >> 1, wc = wid & 1;
  const int wg = blockIdx.x;
  const size_t slot0 = (size_t)t * (BB * 2048);
  const size_t slot1 = slot0 + BB * 2048;
  const u16* px = a.Pcat + (size_t)t * (BB * NPRE);
  const int par = t & 1;
  if (wg < 32) {
    const int m0 = (wg >> 4) << 6, n0 = (wg & 15) << 6;
    {
      const int r = tid >> 2, kb = (tid & 3) << 6;
      const int b = m0 + r;
      const float* rp0 = a.rcp0 + b * DD;
      const float* rp1 = a.rcp1 + b * DD;
      const float* dold = a.d0 + par * (BB * DD) + b * DD;
      float* dnew = a.d0 + (par ^ 1) * (BB * DD) + b * DD;
      const u16* pxr = px + (size_t)b * NPRE + 8192;
      for (int kk = 0; kk < 64; ++kk) {
        const int k = kb + kk;
        const float rc = 0.5f * (rp0[k] + rp1[k] + a.hb0[k] + a.hb1[k]);
        const float dt = sigm(bf2f(pxr[k]) + rc) * dold[k];
        if (n0 == 0) dnew[k] = dt;
        ldsA[r * 264 + k] = f2bf(dt);
      }
    }
    f32x4 acc[2][2] = {};
    gemm_ccA(a.dc0T + (size_t)n0 * DD, ldsA, ldsB, acc);
    EPI(const float gi = a.g0buf[row * H4 + col];
        const float gf = a.g0buf[row * H4 + HH + col];
        const float go = a.g0buf[row * H4 + 2 * HH + col];
        const float gc = a.g0buf[row * H4 + 3 * HH + col];
        float c = sigm(gf) * a.c0[row * HH + col] + sigm(gi) * tanhf(gc) + tanhf(av);
        a.c0[row * HH + col] = c;
        a.hist[slot1 + (size_t)row * 2048 + col] = f2bf(sigm(go) * tanhf(c)););
  } else if (wg < 40) {
    const int jid = wg - 32;
    const int rr = (jid << 4) + (tid >> 4);
    const int cc = 1024 + ((tid & 15) << 6);
    const u16* srcp = a.hist + slot0 + (size_t)rr * 2048 + cc;
    u16* dstp = a.hist + slot1 + (size_t)rr * 2048 + cc;
#pragma unroll
    for (int q = 0; q < 8; ++q) *(uint4*)(dstp + q * 8) = *(const uint4*)(srcp + q * 8);
  }
}

// Stage 3: g1 partials (2x K=1024) ; r1 -> dt1 (K=1024). grid=264
__global__ __launch_bounds__(256) void stage3(SeqArgs a, int t) {
  __shared__ __align__(16) u16 ldsA[64 * 72];
  __shared__ __align__(16) u16 ldsB[64 * 72];
  const int tid = threadIdx.x, lane = tid & 63, wid = tid >> 6;
  const int wr = wid >> 1, wc = wid & 1;
  const int wg = blockIdx.x;
  const size_t slot1 = (size_t)(t + 1) * (BB * 2048);
  const u16* px = a.Pcat + (size_t)t * (BB * NPRE);
  const int par = t & 1;
  if (wg < 128) {
    const int m0 = (wg >> 6) << 6, n0 = (wg & 63) << 6;
    f32x4 acc[2][2] = {};
    gemm64(a.hist + slot1 + (size_t)m0 * 2048, 2048, a.w1sT + (size_t)n0 * 2048, 2048, HH,
           ldsA, ldsB, acc);
    EPI(a.g1p0[row * H4 + col] = av + bf2f(px[(size_t)row * NPRE + 4096 + col]););
  } else if (wg < 256) {
    const int jid = wg - 128;
    const int m0 = (jid >> 6) << 6, n0 = (jid & 63) << 6;
    f32x4 acc[2][2] = {};
    gemm64(a.hist + slot1 + (size_t)m0 * 2048 + 1024, 2048,
           a.w1sT + (size_t)n0 * 2048 + 1024, 2048, HH, ldsA, ldsB, acc);
    EPI(a.g1p1[row * H4 + col] = av;);
  } else {
    const int jid = wg - 256;
    const int m0 = (jid >> 2) << 6, n0 = (jid & 3) << 6;
    f32x4 acc[2][2] = {};
    gemm64(a.hist + slot1 + (size_t)m0 * 2048, 2048, a.w2hr1hT + (size_t)n0 * HH, HH, HH,
           ldsA, ldsB, acc);
    EPI(const float rc =
            0.5f * (a.rcp0[row * DD + col] + a.rcp1[row * DD + col] + a.hb0[col] + a.hb1[col]);
        const float r1 = bf2f(px[(size_t)row * NPRE + 8448 + col]) + rc + av;
        const float dt = sigm(r1) * a.d1[par * (BB * DD) + row * DD + col];
        a.d1[(par ^ 1) * (BB * DD) + row * DD + col] = dt;
        a.dt1bf[row * DD + col] = f2bf(dt););
  }
}

// Stage 4: cc1 (K=256) -> c1,h1. grid=32
__global__ __launch_bounds__(256) void stage4(SeqArgs a, int t) {
  __shared__ __align__(16) u16 ldsA[64 * 72];
  __shared__ __align__(16) u16 ldsB[64 * 72];
  const int tid = threadIdx.x, lane = tid & 63, wid = tid >> 6;
  const int wr = wid >> 1, wc = wid & 1;
  const int wg = blockIdx.x;
  const size_t slot1 = (size_t)(t + 1) * (BB * 2048);
  const int m0 = (wg >> 4) << 6, n0 = (wg & 15) << 6;
  f32x4 acc[2][2] = {};
  gemm64(a.dt1bf + (size_t)m0 * DD, DD, a.dc1T + (size_t)n0 * DD, DD, DD, ldsA, ldsB, acc);
  EPI(const float gi = a.g1p0[row * H4 + col] + a.g1p1[row * H4 + col];
      const float gf = a.g1p0[row * H4 + HH + col] + a.g1p1[row * H4 + HH + col];
      const float go = a.g1p0[row * H4 + 2 * HH + col] + a.g1p1[row * H4 + 2 * HH + col];
      const float gc = a.g1p0[row * H4 + 3 * HH + col] + a.g1p1[row * H4 + 3 * HH + col];
      float c = sigm(gf) * a.c1[row * HH + col] + sigm(gi) * tanhf(gc) + tanhf(av);
      a.c1[row * HH + col] = c;
      a.hist[slot1 + (size_t)row * 2048 + 1024 + col] = f2bf(sigm(go) * tanhf(c)););
}

// ---------------------------------------------------------------------------
extern "C" void kernel_launch(void* const* d_in, const int* in_sizes, int n_in,
                              void* d_out, int out_size, void* d_ws, size_t ws_size,
                              hipStream_t stream) {
  const float* in_seq  = (const float*)d_in[0];
  const float* h0      = (const float*)d_in[1];
  const float* dt0     = (const float*)d_in[2];
  const float* w2h_W0  = (const float*)d_in[3];
  const float* w2h_b0  = (const float*)d_in[4];
  const float* w2h_W1  = (const float*)d_in[5];
  const float* w2h_b1  = (const float*)d_in[6];
  const float* w2hr_W0 = (const float*)d_in[7];
  const float* w2hr_b0 = (const float*)d_in[8];
  const float* w2hr_W1 = (const float*)d_in[9];
  const float* w2hr_b1 = (const float*)d_in[10];
  const float* h2h_W0  = (const float*)d_in[11];
  const float* h2h_b0  = (const float*)d_in[12];
  const float* h2h_W1  = (const float*)d_in[13];
  const float* h2h_b1  = (const float*)d_in[14];
  const float* h2hr_W0 = (const float*)d_in[15];
  const float* h2hr_b0 = (const float*)d_in[16];
  const float* h2hr_W1 = (const float*)d_in[17];
  const float* h2hr_b1 = (const float*)d_in[18];
  const float* dc_W0   = (const float*)d_in[19];
  const float* dc_W1   = (const float*)d_in[20];
  const float* out_W   = (const float*)d_in[21];
  const float* out_b   = (const float*)d_in[22];
  float* out = (float*)d_out;

  char* w = (char*)d_ws;
  auto alloc = [&](size_t bytes) {
    char* p = w;
    w += (bytes + 255) & ~(size_t)255;
    return p;
  };
  u16* xs      = (u16*)alloc((size_t)MPRE * EE * 2);
  u16* BpreT   = (u16*)alloc((size_t)NPRE * EE * 2);
  u16* Pcat    = (u16*)alloc((size_t)MPRE * NPRE * 2);
  u16* h2h0T   = (u16*)alloc((size_t)H4 * HH * 2);
  u16* w1sT    = (u16*)alloc((size_t)H4 * 2048 * 2);
  u16* hrsT    = (u16*)alloc((size_t)DD * 2048 * 2);
  u16* w2hr1hT = (u16*)alloc((size_t)DD * HH * 2);
  u16* dc0T    = (u16*)alloc((size_t)HH * DD * 2);
  u16* dc1T    = (u16*)alloc((size_t)HH * DD * 2);
  u16* outWT   = (u16*)alloc((size_t)VV * 2048 * 2);
  float* biascat = (float*)alloc((size_t)NPRE * 4);
  u16* hist    = (u16*)alloc((size_t)(TT + 1) * BB * 2048 * 2);
  float* g0buf = (float*)alloc((size_t)BB * H4 * 4);
  float* g1p0  = (float*)alloc((size_t)BB * H4 * 4);
  float* g1p1  = (float*)alloc((size_t)BB * H4 * 4);
  float* rcp0  = (float*)alloc((size_t)BB * DD * 4);
  float* rcp1  = (float*)alloc((size_t)BB * DD * 4);
  float* c0    = (float*)alloc((size_t)BB * HH * 4);
  float* c1    = (float*)alloc((size_t)BB * HH * 4);
  float* d0    = (float*)alloc((size_t)2 * BB * DD * 4);
  float* d1    = (float*)alloc((size_t)2 * BB * DD * 4);
  u16* dt1bf   = (u16*)alloc((size_t)BB * DD * 2);

  build_xs<<<MPRE, 256, 0, stream>>>(in_seq, xs);

  dim3 tb(32, 8);
  tconv<<<dim3(128, 64), tb, 0, stream>>>(w2h_W0, 4096, BpreT, 2048);
  tconv<<<dim3(128, 64), tb, 0, stream>>>(w2h_W1, 4096, BpreT + (size_t)4096 * 2048, 2048);
  tconv<<<dim3(8, 64), tb, 0, stream>>>(w2hr_W0, 256, BpreT + (size_t)8192 * 2048, 2048);
  tconv<<<dim3(8, 64), tb, 0, stream>>>(w2hr_W1, 256, BpreT + (size_t)8448 * 2048, 2048);
  tconv<<<dim3(128, 32), tb, 0, stream>>>(h2h_W0, 4096, h2h0T, 1024);
  tconv<<<dim3(128, 32), tb, 0, stream>>>(w2h_W1 + (size_t)2048 * 4096, 4096, w1sT, 2048);
  tconv<<<dim3(128, 32), tb, 0, stream>>>(h2h_W1, 4096, w1sT + 1024, 2048);
  tconv<<<dim3(8, 32), tb, 0, stream>>>(h2hr_W0, 256, hrsT, 2048);
  tconv<<<dim3(8, 32), tb, 0, stream>>>(h2hr_W1, 256, hrsT + 1024, 2048);
  tconv<<<dim3(8, 32), tb, 0, stream>>>(w2hr_W1 + (size_t)2048 * 256, 256, w2hr1hT, 1024);
  tconv<<<dim3(32, 8), tb, 0, stream>>>(dc_W0, 1024, dc0T, 256);
  tconv<<<dim3(32, 8), tb, 0, stream>>>(dc_W1, 1024, dc1T, 256);
  tconv<<<dim3(64, 64), tb, 0, stream>>>(out_W, 2048, outWT, 2048);

  k_biascat<<<(NPRE + 255) / 256, 256, 0, stream>>>(w2h_b0, h2h_b0, w2h_b1, h2h_b1,
                                                    w2hr_b0, w2hr_b1, biascat);
  k_init<<<(BB * 2048) / 256, 256, 0, stream>>>(h0, dt0, hist, c0, c1, d0, d1);

  gemm_big<0><<<(MPRE / 128) * (NPRE / 128), 256, 0, stream>>>(xs, BpreT, biascat, Pcat,
                                                               NPRE, EE);

  SeqArgs sa;
  sa.Pcat = Pcat; sa.h2h0T = h2h0T; sa.w1sT = w1sT; sa.hrsT = hrsT;
  sa.w2hr1hT = w2hr1hT; sa.dc0T = dc0T; sa.dc1T = dc1T;
  sa.hb0 = h2hr_b0; sa.hb1 = h2hr_b1;
  sa.hist = hist; sa.g0buf = g0buf; sa.g1p0 = g1p0; sa.g1p1 = g1p1;
  sa.rcp0 = rcp0; sa.rcp1 = rcp1; sa.c0 = c0; sa.c1 = c1;
  sa.d0 = d0; sa.d1 = d1; sa.dt1bf = dt1bf;

  for (int t = 0; t < TT; ++t) {
    stage1<<<144, 256, 0, stream>>>(sa, t);
    stage2<<<40, 256, 0, stream>>>(sa, t);
    stage3<<<264, 256, 0, stream>>>(sa, t);
    stage4<<<32, 256, 0, stream>>>(sa, t);
  }

  gemm_big<1><<<(MPRE / 128) * (VV / 128), 256, 0, stream>>>(hist + (size_t)BB * 2048, outWT,
                                                             out_b, out, VV, 2048);
}